// Round 1
// baseline (211.251 us; speedup 1.0000x reference)
//
#include <hip/hip_runtime.h>

#define N_TOK 2048
#define DD 512
#define FF 512
#define EE 64
#define TK 6
#define NG 66
#define RSLOT 12288   // N_TOK*TK
#define NSLOT 16384   // RSLOT + 2*N_TOK
#define BM 64
#define BN 64

typedef float f32x4 __attribute__((ext_vector_type(4)));
typedef __bf16 bf16x8 __attribute__((ext_vector_type(8)));
typedef short s16x8 __attribute__((ext_vector_type(8)));

__device__ __forceinline__ short f2bf(float f) {
  unsigned u = __builtin_bit_cast(unsigned, f);
  u = (u + 0x7fffu + ((u >> 16) & 1u)) >> 16;
  return (short)u;
}

// ---------------- router: logits -> exp(l-max) -> top-6 + counts ----------------
__global__ void router_k(const float* __restrict__ x, const float* __restrict__ Wr,
                         int* __restrict__ top_i, float* __restrict__ top_w,
                         int* __restrict__ cnt) {
  int wave = threadIdx.x >> 6, lane = threadIdx.x & 63;
  int t0 = (blockIdx.x * 4 + wave) * 4;   // 4 tokens per wave
  const float* x0 = x + (size_t)t0 * DD;
  float a0 = 0.f, a1 = 0.f, a2 = 0.f, a3 = 0.f;
  for (int k = 0; k < DD; ++k) {
    float wv = Wr[k * EE + lane];
    a0 = fmaf(x0[k], wv, a0);
    a1 = fmaf(x0[DD + k], wv, a1);
    a2 = fmaf(x0[2 * DD + k], wv, a2);
    a3 = fmaf(x0[3 * DD + k], wv, a3);
  }
  float accs[4] = {a0, a1, a2, a3};
#pragma unroll
  for (int tt = 0; tt < 4; ++tt) {
    int t = t0 + tt;
    float acc = accs[tt];
    float m = acc;
#pragma unroll
    for (int s = 32; s; s >>= 1) m = fmaxf(m, __shfl_xor(m, s));
    float p = __expf(acc - m);   // unnormalized softmax; ratios identical
    int wi[TK]; float wv[TK];
#pragma unroll
    for (int it = 0; it < TK; ++it) {
      float v = p;
#pragma unroll
      for (int s = 32; s; s >>= 1) v = fmaxf(v, __shfl_xor(v, s));
      unsigned long long b = __ballot(p == v);
      int idx = __ffsll((unsigned long long)b) - 1;
      wi[it] = idx; wv[it] = v;
      if (lane == idx) p = -1.f;
    }
    float wsum = 0.f;
#pragma unroll
    for (int it = 0; it < TK; ++it) wsum += wv[it];
    if (lane < TK) {
      int si = 0; float sv = 0.f;
#pragma unroll
      for (int it = 0; it < TK; ++it) if (lane == it) { si = wi[it]; sv = wv[it]; }
      top_i[t * TK + lane] = si;
      top_w[t * TK + lane] = sv / wsum;
      atomicAdd(&cnt[si], 1);
    }
  }
}

// ---------------- offsets: prefix sum over experts, zero fill ----------------
__global__ void offsets_k(const int* __restrict__ cnt, int* __restrict__ goff,
                          int* __restrict__ fill) {
  int i = threadIdx.x;
  if (i < EE) fill[i] = 0;
  if (i == 0) {
    int s = 0;
    for (int e = 0; e < EE; ++e) { goff[e] = s; s += cnt[e]; }
    goff[EE] = RSLOT;
    goff[EE + 1] = RSLOT + N_TOK;
    goff[EE + 2] = RSLOT + 2 * N_TOK;
  }
}

// ---------------- scatter: fill expert buckets (+ shared identity buckets) -----
__global__ void scatter_k(const int* __restrict__ top_i, const float* __restrict__ top_w,
                          const int* __restrict__ goff, int* __restrict__ fill,
                          int* __restrict__ btok, float* __restrict__ bw) {
  int idx = blockIdx.x * blockDim.x + threadIdx.x;
  if (idx < RSLOT) {
    int e = top_i[idx];
    int pos = goff[e] + atomicAdd(&fill[e], 1);
    btok[pos] = idx / TK;
    bw[pos] = top_w[idx];
  } else if (idx < NSLOT) {
    int j = idx - RSLOT;
    btok[idx] = j & (N_TOK - 1);
    bw[idx] = 1.0f;
  }
}

// ---------------- out = x (residual init) ----------------
__global__ void initout_k(const float* __restrict__ x, float* __restrict__ out, int n4) {
  int i = blockIdx.x * blockDim.x + threadIdx.x;
  if (i < n4) reinterpret_cast<f32x4*>(out)[i] = reinterpret_cast<const f32x4*>(x)[i];
}

// ---------------- GEMM1: H = silu(X*Wg) * (X*Wu), gathered rows -------------
__global__ __launch_bounds__(256) void gemm1_k(
    const float* __restrict__ x, const float* __restrict__ Wg, const float* __restrict__ Wu,
    const float* __restrict__ sWg, const float* __restrict__ sWu,
    const int* __restrict__ goff, const int* __restrict__ btok,
    short* __restrict__ H) {
  int g = blockIdx.z;
  int s0g = goff[g], cnt = goff[g + 1] - s0g;
  int mt = blockIdx.y;
  if (mt * BM >= cnt) return;
  int n0 = blockIdx.x * BN;
  const float* wgp = (g < EE) ? Wg + (size_t)g * DD * FF : sWg + (size_t)(g - EE) * DD * FF;
  const float* wup = (g < EE) ? Wu + (size_t)g * DD * FF : sWu + (size_t)(g - EE) * DD * FF;

  __shared__ short laA[4][BM][8];
  __shared__ short lbG[4][BN][8];
  __shared__ short lbU[4][BN][8];

  int tid = threadIdx.x;
  int lane = tid & 63;
  int w = tid >> 6;
  int wr = w >> 1, wc = w & 1;
  int lr = lane & 15, lgq = lane >> 4;

  int sm = tid >> 2, skb = tid & 3;     // A staging: row, kblk
  int sn = tid & 63, skb2 = tid >> 6;   // B staging: col, kblk

  int s0 = s0g + mt * BM;
  int tok = btok[((mt * BM + sm) < cnt) ? (s0 + sm) : s0];
  const float* xrow = x + (size_t)tok * DD;

  f32x4 accg[2][2], accu[2][2];
#pragma unroll
  for (int i = 0; i < 2; ++i)
#pragma unroll
    for (int j = 0; j < 2; ++j) {
      accg[i][j] = f32x4{0.f, 0.f, 0.f, 0.f};
      accu[i][j] = f32x4{0.f, 0.f, 0.f, 0.f};
    }

  for (int kt = 0; kt < DD / 32; ++kt) {
    int k0 = kt * 32;
    __syncthreads();
    { // stage A (gathered token rows, f32 -> bf16)
      const float* p = xrow + k0 + skb * 8;
      f32x4 v0 = *reinterpret_cast<const f32x4*>(p);
      f32x4 v1 = *reinterpret_cast<const f32x4*>(p + 4);
      s16x8 o;
      o[0] = f2bf(v0[0]); o[1] = f2bf(v0[1]); o[2] = f2bf(v0[2]); o[3] = f2bf(v0[3]);
      o[4] = f2bf(v1[0]); o[5] = f2bf(v1[1]); o[6] = f2bf(v1[2]); o[7] = f2bf(v1[3]);
      *reinterpret_cast<s16x8*>(&laA[skb][sm][0]) = o;
    }
    { // stage B: transpose-gather Wg/Wu columns, f32 -> bf16
      const float* bgp = wgp + (size_t)(k0 + skb2 * 8) * FF + n0 + sn;
      const float* bup = wup + (size_t)(k0 + skb2 * 8) * FF + n0 + sn;
      s16x8 og, ou;
#pragma unroll
      for (int i = 0; i < 8; ++i) {
        og[i] = f2bf(bgp[(size_t)i * FF]);
        ou[i] = f2bf(bup[(size_t)i * FF]);
      }
      *reinterpret_cast<s16x8*>(&lbG[skb2][sn][0]) = og;
      *reinterpret_cast<s16x8*>(&lbU[skb2][sn][0]) = ou;
    }
    __syncthreads();
    bf16x8 af[2], bgf[2], buf[2];
#pragma unroll
    for (int i = 0; i < 2; ++i)
      af[i] = *reinterpret_cast<const bf16x8*>(&laA[lgq][wr * 32 + i * 16 + lr][0]);
#pragma unroll
    for (int j = 0; j < 2; ++j) {
      bgf[j] = *reinterpret_cast<const bf16x8*>(&lbG[lgq][wc * 32 + j * 16 + lr][0]);
      buf[j] = *reinterpret_cast<const bf16x8*>(&lbU[lgq][wc * 32 + j * 16 + lr][0]);
    }
#pragma unroll
    for (int i = 0; i < 2; ++i)
#pragma unroll
      for (int j = 0; j < 2; ++j) {
        accg[i][j] = __builtin_amdgcn_mfma_f32_16x16x32_bf16(af[i], bgf[j], accg[i][j], 0, 0, 0);
        accu[i][j] = __builtin_amdgcn_mfma_f32_16x16x32_bf16(af[i], buf[j], accu[i][j], 0, 0, 0);
      }
  }
  // epilogue: h = silu(g)*u -> bf16 H
#pragma unroll
  for (int i = 0; i < 2; ++i)
#pragma unroll
    for (int j = 0; j < 2; ++j)
#pragma unroll
      for (int r = 0; r < 4; ++r) {
        int mrow = wr * 32 + i * 16 + lgq * 4 + r;
        if (mt * BM + mrow < cnt) {
          float gg = accg[i][j][r];
          float uu = accu[i][j][r];
          float hv = (gg / (1.f + __expf(-gg))) * uu;
          int col = n0 + wc * 32 + j * 16 + lr;
          H[(size_t)(s0 + mrow) * FF + col] = f2bf(hv);
        }
      }
}

// ---------------- GEMM2: out[tok] += w * (H * Wd) ----------------
__global__ __launch_bounds__(256) void gemm2_k(
    const short* __restrict__ H, const float* __restrict__ Wd, const float* __restrict__ sWd,
    const int* __restrict__ goff, const int* __restrict__ btok, const float* __restrict__ bw,
    float* __restrict__ out) {
  int g = blockIdx.z;
  int s0g = goff[g], cnt = goff[g + 1] - s0g;
  int mt = blockIdx.y;
  if (mt * BM >= cnt) return;
  int n0 = blockIdx.x * BN;
  const float* wdp = (g < EE) ? Wd + (size_t)g * FF * DD : sWd + (size_t)(g - EE) * FF * DD;

  __shared__ short laA[4][BM][8];
  __shared__ short lbB[4][BN][8];

  int tid = threadIdx.x;
  int lane = tid & 63;
  int w = tid >> 6;
  int wr = w >> 1, wc = w & 1;
  int lr = lane & 15, lgq = lane >> 4;

  int sm = tid >> 2, skb = tid & 3;
  int sn = tid & 63, skb2 = tid >> 6;

  int s0 = s0g + mt * BM;
  int srow = s0 + sm;
  if (srow > NSLOT - 1) srow = NSLOT - 1;
  const short* hrow = H + (size_t)srow * FF;

  f32x4 acc[2][2];
#pragma unroll
  for (int i = 0; i < 2; ++i)
#pragma unroll
    for (int j = 0; j < 2; ++j) acc[i][j] = f32x4{0.f, 0.f, 0.f, 0.f};

  for (int kt = 0; kt < FF / 32; ++kt) {
    int k0 = kt * 32;
    __syncthreads();
    { // stage A from H (already bf16)
      s16x8 v = *reinterpret_cast<const s16x8*>(hrow + k0 + skb * 8);
      *reinterpret_cast<s16x8*>(&laA[skb][sm][0]) = v;
    }
    { // stage B: transpose-gather Wd
      const float* bp = wdp + (size_t)(k0 + skb2 * 8) * DD + n0 + sn;
      s16x8 ob;
#pragma unroll
      for (int i = 0; i < 8; ++i) ob[i] = f2bf(bp[(size_t)i * DD]);
      *reinterpret_cast<s16x8*>(&lbB[skb2][sn][0]) = ob;
    }
    __syncthreads();
    bf16x8 af[2], bf[2];
#pragma unroll
    for (int i = 0; i < 2; ++i)
      af[i] = *reinterpret_cast<const bf16x8*>(&laA[lgq][wr * 32 + i * 16 + lr][0]);
#pragma unroll
    for (int j = 0; j < 2; ++j)
      bf[j] = *reinterpret_cast<const bf16x8*>(&lbB[lgq][wc * 32 + j * 16 + lr][0]);
#pragma unroll
    for (int i = 0; i < 2; ++i)
#pragma unroll
      for (int j = 0; j < 2; ++j)
        acc[i][j] = __builtin_amdgcn_mfma_f32_16x16x32_bf16(af[i], bf[j], acc[i][j], 0, 0, 0);
  }
#pragma unroll
  for (int i = 0; i < 2; ++i)
#pragma unroll
    for (int j = 0; j < 2; ++j)
#pragma unroll
      for (int r = 0; r < 4; ++r) {
        int mrow = wr * 32 + i * 16 + lgq * 4 + r;
        if (mt * BM + mrow < cnt) {
          int slot = s0 + mrow;
          int tok = btok[slot];
          float wv = bw[slot];
          int col = n0 + wc * 32 + j * 16 + lr;
          atomicAdd(&out[(size_t)tok * DD + col], acc[i][j][r] * wv);
        }
      }
}

extern "C" void kernel_launch(void* const* d_in, const int* in_sizes, int n_in,
                              void* d_out, int out_size, void* d_ws, size_t ws_size,
                              hipStream_t stream) {
  const float* x   = (const float*)d_in[0];
  const float* Wr  = (const float*)d_in[1];
  const float* sWg = (const float*)d_in[2];
  const float* sWu = (const float*)d_in[3];
  const float* sWd = (const float*)d_in[4];
  const float* Wg  = (const float*)d_in[5];
  const float* Wu  = (const float*)d_in[6];
  const float* Wd  = (const float*)d_in[7];
  float* out = (float*)d_out;

  char* wsb = (char*)d_ws;
  size_t off = 0;
  short* H = (short*)(wsb + off);    off += (size_t)NSLOT * FF * 2;     // 16 MB
  int*   top_i = (int*)(wsb + off);  off += (size_t)RSLOT * 4;
  float* top_w = (float*)(wsb + off); off += (size_t)RSLOT * 4;
  int*   btok = (int*)(wsb + off);   off += (size_t)NSLOT * 4;
  float* bwt  = (float*)(wsb + off); off += (size_t)NSLOT * 4;
  int*   cnt  = (int*)(wsb + off);   off += 256;
  int*   fill = (int*)(wsb + off);   off += 256;
  int*   goff = (int*)(wsb + off);   off += 256;

  hipMemsetAsync(cnt, 0, 256, stream);
  router_k<<<N_TOK / 16, 256, 0, stream>>>(x, Wr, top_i, top_w, cnt);
  offsets_k<<<1, 64, 0, stream>>>(cnt, goff, fill);
  scatter_k<<<NSLOT / 256, 256, 0, stream>>>(top_i, top_w, goff, fill, btok, bwt);
  int n4 = out_size / 4;
  initout_k<<<(n4 + 255) / 256, 256, 0, stream>>>(x, out, n4);
  dim3 grid1(FF / BN, N_TOK / BM, NG);
  gemm1_k<<<grid1, 256, 0, stream>>>(x, Wg, Wu, sWg, sWu, goff, btok, H);
  dim3 grid2(DD / BN, N_TOK / BM, NG);
  gemm2_k<<<grid2, 256, 0, stream>>>(H, Wd, sWd, goff, btok, bwt, out);
}